// Round 5
// baseline (389.267 us; speedup 1.0000x reference)
//
#include <hip/hip_runtime.h>

#define B_  64
#define T_  1024
#define FC_ 256
#define FX_ 512

typedef __bf16 bf16x8 __attribute__((ext_vector_type(8)));
typedef float  f32x4  __attribute__((ext_vector_type(4)));

__device__ __forceinline__ unsigned short f2bf(float f) {
  union { float f; unsigned int u; } v; v.f = f;
  unsigned int r = v.u + 0x7fffu + ((v.u >> 16) & 1u);  // RNE
  return (unsigned short)(r >> 16);
}
__device__ __forceinline__ unsigned int pk2(float lo, float hi) {
  return (unsigned int)f2bf(lo) | ((unsigned int)f2bf(hi) << 16);
}
__device__ __forceinline__ bf16x8 pk8(float4 a, float4 b) {
  uint4 p;
  p.x = pk2(a.x, a.y); p.y = pk2(a.z, a.w);
  p.z = pk2(b.x, b.y); p.w = pk2(b.z, b.w);
  return __builtin_bit_cast(bf16x8, p);
}

// ---------------------------------------------------------------------------
// Prep: W f32 [256][512] -> bf16 ws; zero the scalar output.
// ---------------------------------------------------------------------------
__global__ __launch_bounds__(256)
void k_wcvt(const float* __restrict__ W, unsigned short* __restrict__ Wb,
            float* __restrict__ out) {
  const int i = blockIdx.x * 256 + threadIdx.x;   // 32768 float4-groups
  float4 v = ((const float4*)W)[i];
  ushort4 h;
  h.x = f2bf(v.x); h.y = f2bf(v.y); h.z = f2bf(v.z); h.w = f2bf(v.w);
  ((ushort4*)Wb)[i] = h;
  if (i == 0) out[0] = 0.f;
}

// ---------------------------------------------------------------------------
// k1: Xt[m, c] = sum_x X[m, x] * W[c, x] + b[c]   (M=65536, N=256, K=512)
// Pure streaming, NO LDS, NO barriers. Block = 64 rows (4 waves x 16 rows),
// each wave computes its 16 rows x all 256 cols (16 n-frags, acc[16]).
// A-frags: X direct from global in fragment layout, f32->bf16 in-reg.
// B-frags: W bf16 from L2 (256 KB, resident). Output Xt bf16 [m][c] to ws.
// ---------------------------------------------------------------------------
__global__ __launch_bounds__(256, 4)
void k1_xt(const float* __restrict__ X, const unsigned short* __restrict__ Wb,
           const float* __restrict__ bias, unsigned short* __restrict__ Xt)
{
  const int tid  = threadIdx.x;
  const int lane = tid & 63;
  const int wid  = tid >> 6;            // 0..3
  const int l15  = lane & 15;
  const int lhi  = lane >> 4;           // 0..3
  const int m0   = blockIdx.x * 64 + wid * 16;

  const float* xrow  = X + (size_t)(m0 + l15) * FX_ + lhi * 8;
  const char*  wbase = (const char*)Wb + (size_t)l15 * 1024 + lhi * 16;

  f32x4 acc[16];
  #pragma unroll
  for (int n = 0; n < 16; ++n)
    #pragma unroll
    for (int r = 0; r < 4; ++r) acc[n][r] = 0.f;

  #pragma unroll
  for (int s = 0; s < 16; ++s) {        // K slices of 32
    float4 a0 = *(const float4*)(xrow + s * 32);
    float4 a1 = *(const float4*)(xrow + s * 32 + 4);
    bf16x8 av = pk8(a0, a1);
    #pragma unroll
    for (int g = 0; g < 2; ++g) {       // n2 groups of 8 (bounds VGPR peak)
      bf16x8 wv[8];
      #pragma unroll
      for (int j = 0; j < 8; ++j)
        wv[j] = *(const bf16x8*)(wbase + (size_t)(g * 8 + j) * 16384 + s * 64);
      #pragma unroll
      for (int j = 0; j < 8; ++j)
        acc[g * 8 + j] = __builtin_amdgcn_mfma_f32_16x16x32_bf16(av, wv[j], acc[g * 8 + j], 0, 0, 0);
    }
  }

  // epilogue: +bias, cvt, store.  C/D layout: col = l15, row = lhi*4 + r.
  #pragma unroll
  for (int n = 0; n < 16; ++n) {
    const float bb = bias[n * 16 + l15];
    #pragma unroll
    for (int r = 0; r < 4; ++r) {
      const int m = m0 + lhi * 4 + r;
      Xt[(size_t)m * FC_ + n * 16 + l15] = f2bf(acc[n][r] + bb);
    }
  }
}

// ---------------------------------------------------------------------------
// k2: per t: Z = C_t · Xt_t^T (64x64, K=256), row-lse + diag, atomicAdd.
// NO LDS, no staging: C A-frags direct from global (f32->bf16 in-reg),
// Xt B-frags direct from global (bf16, L3-hot). 4 waves, wave w = Z rows 16w.
// ---------------------------------------------------------------------------
__global__ __launch_bounds__(256, 4)
void k2_loss(const float* __restrict__ C, const unsigned short* __restrict__ Xt,
             float* __restrict__ out)
{
  const int t    = blockIdx.x;
  const int tid  = threadIdx.x;
  const int lane = tid & 63;
  const int wid  = tid >> 6;            // 0..3
  const int l15  = lane & 15;
  const int lhi  = lane >> 4;           // 0..3

  // C fragment source: row i = wid*16 + l15, k-offset lhi*8 (f32)
  const float* cptr = C + ((size_t)(wid * 16 + l15) * T_ + t) * FC_ + lhi * 8;
  float4 cv[16];
  #pragma unroll
  for (int q = 0; q < 8; ++q) {
    cv[2 * q]     = *(const float4*)(cptr + 32 * q);
    cv[2 * q + 1] = *(const float4*)(cptr + 32 * q + 4);
  }

  // Xt fragment source: row j = n*16 + l15  -> byte j*524288 + t*512;
  // k-offset: s*64 + lhi*16 bytes.
  const char* xb = (const char*)Xt + (size_t)l15 * (T_ * FC_ * 2) + (size_t)t * (FC_ * 2) + lhi * 16;

  f32x4 z[4];
  #pragma unroll
  for (int n = 0; n < 4; ++n)
    #pragma unroll
    for (int r = 0; r < 4; ++r) z[n][r] = 0.f;

  #pragma unroll
  for (int s = 0; s < 8; ++s) {         // K slices of 32
    bf16x8 ca = pk8(cv[2 * s], cv[2 * s + 1]);
    #pragma unroll
    for (int n = 0; n < 4; ++n) {
      bf16x8 b = *(const bf16x8*)(xb + (size_t)n * 16 * (T_ * FC_ * 2) + s * 64);
      z[n] = __builtin_amdgcn_mfma_f32_16x16x32_bf16(ca, b, z[n], 0, 0, 0);
    }
  }

  // row i = 16*wid + 4*lhi + r ; col j = 16n + l15
  float partial = 0.f;
  #pragma unroll
  for (int r = 0; r < 4; ++r) {
    float m = fmaxf(fmaxf(z[0][r], z[1][r]), fmaxf(z[2][r], z[3][r]));
    #pragma unroll
    for (int d = 1; d < 16; d <<= 1) m = fmaxf(m, __shfl_xor(m, d));
    float s = __expf(z[0][r] - m) + __expf(z[1][r] - m) +
              __expf(z[2][r] - m) + __expf(z[3][r] - m);
    #pragma unroll
    for (int d = 1; d < 16; d <<= 1) s += __shfl_xor(s, d);
    const float lse = m + __logf(s);
    float dv = 0.f;
    #pragma unroll
    for (int n = 0; n < 4; ++n) dv = (n == wid) ? z[n][r] : dv;  // static idx
    if (l15 == lhi * 4 + r) partial += dv - lse;
  }
  #pragma unroll
  for (int d = 1; d < 64; d <<= 1) partial += __shfl_xor(partial, d);
  if (lane == 0) atomicAdd(out, partial * (1.0f / (B_ * T_)));
}

extern "C" void kernel_launch(void* const* d_in, const int* in_sizes, int n_in,
                              void* d_out, int out_size, void* d_ws, size_t ws_size,
                              hipStream_t stream) {
  const float* C  = (const float*)d_in[0];
  const float* X  = (const float*)d_in[1];
  const float* W  = (const float*)d_in[2];
  const float* bb = (const float*)d_in[3];
  unsigned short* Wb = (unsigned short*)d_ws;            // 256 KB bf16 W
  unsigned short* Xt = (unsigned short*)d_ws + 131072;   // 32 MB bf16 Xt
  float* out = (float*)d_out;

  k_wcvt <<<dim3(128),  dim3(256), 0, stream>>>(W, Wb, out);
  k1_xt  <<<dim3(1024), dim3(256), 0, stream>>>(X, Wb, bb, Xt);
  k2_loss<<<dim3(1024), dim3(256), 0, stream>>>(C, Xt, out);
}